// Round 1
// baseline (119.582 us; speedup 1.0000x reference)
//
#include <hip/hip_runtime.h>
#include <math.h>

// Canny-style Sobel NMS + double threshold on 4096x4096 f32.
// Reference's direction predicate b1 is vacuously true -> NMS is horizontal.
//
// R9: rolling-window chunks. R8's wave read 10 input rows per 8 output rows
// (1.25x fetch amplification: ~151 MB total HBM traffic vs 134 MB ideal;
// 151 MB / 6.3 TB/s = 24.0 us matches the observed canny dispatch slice).
// Here each wave owns 32 output rows processed as 4 chunks of 8, keeping the
// 2-row vertical overlap between chunks in registers: 34 rows loaded per 32
// produced (1.0625x). Next-chunk loads (8 coalesced f4 + 1 masked halo f2)
// issue BEFORE the current chunk's math so HBM latency hides under VALU.
// Math identical to the verified absmax-0.0 path: exact squared-domain NMS +
// double threshold with integer hazard net -> rare sqrtf reference fallback.

constexpr int Wd = 4096;
constexpr int Ht = 4096;
constexpr int CH  = 8;   // output rows per chunk
constexpr int NCH = 4;   // chunks per wave -> 32 rows/wave

typedef float f4 __attribute__((ext_vector_type(4)));
typedef float f2 __attribute__((ext_vector_type(2)));

__global__ __launch_bounds__(256) void canny_kernel(const float* __restrict__ x,
                                                    float* __restrict__ out) {
    const int tid  = threadIdx.x;
    const int lane = tid & 63;
    const int wv   = tid >> 6;
    const int wc   = blockIdx.x;                       // 256-col band, 0..15
    const int cbase = wc * 256;
    const int c     = cbase + lane * 4;                // lane's first col
    const int r0    = (blockIdx.y * 4 + wv) * (CH * NCH);  // wave's first row

    // Halo lane roles (fixed for the whole wave):
    // lane k (k<10):  left halo f2 (cols cbase-2, cbase-1) of chunk-row k
    // lane 32+k:      right halo f2 (cols cbase+256, +257) of chunk-row k
    const int  hk     = lane & 31;
    const bool hleft  = lane < 32;
    const bool hvalid = (hk < CH + 2) && (hleft ? (wc > 0) : (wc < 15));
    const int  hc     = hleft ? cbase - 2 : cbase + 256;

    // ---- Initial window: input rows r0-1 .. r0+8 in X[0..9] ----
    f4 X[CH + 2];
    #pragma unroll
    for (int k = 0; k < CH + 2; ++k) {
        int rr = r0 - 1 + k;
        rr = rr < 0 ? 0 : (rr > Ht - 1 ? Ht - 1 : rr);  // edge rows zeroed later
        X[k] = *(const f4*)(x + (size_t)rr * Wd + c);
    }
    f2 hl = {0.f, 0.f};
    if (hvalid) {
        int rr = r0 - 1 + hk;
        rr = rr < 0 ? 0 : rr;
        hl = *(const f2*)(x + (size_t)rr * Wd + hc);
    }

    const float C1  = __uint_as_float(0x3CB851EDu);  // q > C1  <=> sqrt(q) > 0.15f
    const float C2B = __uint_as_float(0x3B23D709u);  // q > C2B <=> sqrt(q) >= 0.05f

    #pragma unroll 1
    for (int chn = 0; chn < NCH; ++chn) {
        const int  rc   = r0 + chn * CH;
        const bool more = (chn < NCH - 1);

        // ---- Issue next chunk's loads first (hide HBM under this chunk's math)
        f4 N[CH];
        f2 hln = {0.f, 0.f};
        if (more) {
            #pragma unroll
            for (int k = 0; k < CH; ++k) {
                int rr = rc + CH + 1 + k;              // rows rc+9 .. rc+16
                rr = rr > Ht - 1 ? Ht - 1 : rr;
                N[k] = *(const f4*)(x + (size_t)rr * Wd + c);
            }
            if (hvalid) {
                int rr = rc + CH - 1 + hk;             // rows rc+7 .. rc+16
                rr = rr > Ht - 1 ? Ht - 1 : rr;
                hln = *(const f2*)(x + (size_t)rr * Wd + hc);
            }
        }

        // ---- Halo vertical pass for this chunk (lane hk holds row rc-1+hk)
        const float s1x = __shfl_down(hl.x, 1), s2x = __shfl_down(hl.x, 2);
        const float s1y = __shfl_down(hl.y, 1), s2y = __shfl_down(hl.y, 2);
        const float th1x = hl.x + 2.0f * s1x + s2x;   // t1 of halo col 0
        const float th1y = hl.y + 2.0f * s1y + s2y;   // t1 of halo col 1
        const float th2x = hl.x - s2x;                // t2 of halo col 0
        const float th2y = hl.y - s2y;                // t2 of halo col 1

        #pragma unroll
        for (int o = 0; o < CH; ++o) {
            const int r = rc + o;
            f4 a = X[o], b = X[o + 1], cc = X[o + 2];

            // Vertical pass for own 4 cols: t1 = a+2b+c (gx), t2 = a-c (gy).
            float t1[4], t2[4];
            #pragma unroll
            for (int j = 0; j < 4; ++j) {
                t1[j] = a[j] + 2.0f * b[j] + cc[j];
                t2[j] = a[j] - cc[j];
            }

            // Halo broadcast: lane 0 wants left (lane o), lane 63 right (32+o).
            const int hidx = (lane == 63) ? 32 + o : o;
            const float b1x = __shfl(th1x, hidx);
            const float b1y = __shfl(th1y, hidx);
            const float b2x = __shfl(th2x, hidx);
            const float b2y = __shfl(th2y, hidx);

            // Neighbor t via shuffle: left lane's cols 2,3 / right lane's 0,1.
            float l1a = __shfl_up(t1[2], 1),   l1b = __shfl_up(t1[3], 1);
            float l2a = __shfl_up(t2[2], 1),   l2b = __shfl_up(t2[3], 1);
            float r1a = __shfl_down(t1[0], 1), r1b = __shfl_down(t1[1], 1);
            float r2a = __shfl_down(t2[0], 1), r2b = __shfl_down(t2[1], 1);
            if (lane == 0)  { l1a = b1x; l1b = b1y; l2a = b2x; l2b = b2y; }
            if (lane == 63) { r1a = b1x; r1b = b1y; r2a = b2x; r2b = b2y; }

            // T index k = image col c + (k-2), k = 0..7.
            float T1[8] = {l1a, l1b, t1[0], t1[1], t1[2], t1[3], r1a, r1b};
            float T2[8] = {l2a, l2b, t2[0], t2[1], t2[2], t2[3], r2a, r2b};

            // Squared gradient magnitude q[i] at image col c + (i-1), i = 0..5.
            float q[6];
            #pragma unroll
            for (int i = 0; i < 6; ++i) {
                float gx = T1[i + 2] - T1[i];
                float gy = T2[i] + 2.0f * T2[i + 1] + T2[i + 2];
                q[i] = gx * gx + gy * gy;
            }

            // Hazard net: near-tie q pairs could flip >= after sqrt rounding.
            bool hazard = false;
            #pragma unroll
            for (int i = 0; i < 5; ++i) {
                int d = (int)(__float_as_uint(q[i + 1]) - __float_as_uint(q[i]));
                hazard |= ((unsigned)(d + 8) < 17u);
            }

            float acc[4];
            #pragma unroll
            for (int o2 = 0; o2 < 4; ++o2) {
                float qp = q[o2], qc = q[o2 + 1], qn = q[o2 + 2];
                bool keep = (qc >= qp) && (qc >= qn);
                acc[o2] = (keep && qc > C1) ? 255.0f : 0.0f;
                hazard |= (keep && qc > 0.0f && qc <= C2B);  // pass-through needs sqrt
            }

            if (__any(hazard)) {
                // Exact reference path (rare).
                float m[6];
                #pragma unroll
                for (int i = 0; i < 6; ++i) m[i] = sqrtf(q[i]);
                #pragma unroll
                for (int o2 = 0; o2 < 4; ++o2) {
                    float mc = m[o2 + 1];
                    bool keep = (mc >= m[o2]) && (mc >= m[o2 + 2]);
                    float e = keep ? mc : 0.0f;
                    acc[o2] = (e > 0.15f) ? 255.0f : ((e >= 0.05f) ? 0.0f : e);
                }
            }

            // Zero border shell, exactly as the reference.
            if (r == 0 || r == Ht - 1) {
                #pragma unroll
                for (int o2 = 0; o2 < 4; ++o2) acc[o2] = 0.0f;
            }
            if (wc == 0  && lane == 0)  acc[0] = 0.0f;
            if (wc == 15 && lane == 63) acc[3] = 0.0f;

            f4 v = {acc[0], acc[1], acc[2], acc[3]};
            __builtin_nontemporal_store(v, (f4*)(out + (size_t)r * Wd + c));
        }

        // ---- Roll the window: rows rc+7, rc+8 stay in registers.
        if (more) {
            X[0] = X[CH];
            X[1] = X[CH + 1];
            #pragma unroll
            for (int k = 0; k < CH; ++k) X[k + 2] = N[k];
            hl = hln;
        }
    }
}

extern "C" void kernel_launch(void* const* d_in, const int* in_sizes, int n_in,
                              void* d_out, int out_size, void* d_ws, size_t ws_size,
                              hipStream_t stream) {
    const float* x = (const float*)d_in[0];
    float* out = (float*)d_out;
    dim3 grid(16, Ht / (4 * CH * NCH));   // 16 col-bands x 32 blocks (4 waves x 32 rows)
    canny_kernel<<<grid, dim3(256), 0, stream>>>(x, out);
}

// Round 2
// 110.690 us; speedup vs baseline: 1.0803x; 1.0803x over previous
//
#include <hip/hip_runtime.h>
#include <math.h>

// Canny-style Sobel NMS + double threshold on 4096x4096 f32.
// Reference's direction predicate b1 is vacuously true -> NMS is horizontal.
//
// R10: flat 16-row waves. R9's rolling-window regressed (119.6 vs R8's 110.4):
// 512 blocks + serialized chunk phases starved DRAM of in-flight requests.
// This keeps R8's proven shape -- ALL loads issued up-front, zero intra-wave
// serialization -- and doubles rows/wave 8->16, cutting vertical-halo read
// amplification 1.25x -> 1.125x (151 MB -> 143 MB total traffic). Grid stays
// 16x64 = 1024 blocks (4/CU); each wave has 18 independent f4 loads (~18 KB)
// in flight, so MLP per CU matches R8 even at reduced occupancy.
// Both column halos for all 18 window rows ride in ONE masked f2 load
// (lane k<18 = left halo of window row k, lane 32+k = right halo); per-lane
// halo t built with 4 shfl_down, consumed via 4 indexed-shfl broadcasts/row.
// Math identical to the verified absmax-0.0 path: exact squared-domain NMS +
// double threshold with integer hazard net -> rare sqrtf reference fallback.

constexpr int Wd = 4096;
constexpr int Ht = 4096;
constexpr int ROWS = 16;

typedef float f4 __attribute__((ext_vector_type(4)));
typedef float f2 __attribute__((ext_vector_type(2)));

__global__ __launch_bounds__(256) void canny_kernel(const float* __restrict__ x,
                                                    float* __restrict__ out) {
    const int tid  = threadIdx.x;
    const int lane = tid & 63;
    const int wv   = tid >> 6;
    const int wc   = blockIdx.x;                     // 256-col band, 0..15
    const int cbase = wc * 256;
    const int c     = cbase + lane * 4;              // lane's first col
    const int r0    = (blockIdx.y * 4 + wv) * ROWS;  // wave's first output row

    // ---- Main loads: 18 coalesced f4 row-chunks (1KB/instruction), all
    // independent, issued before any math. ----
    f4 X[ROWS + 2];
    #pragma unroll
    for (int k = 0; k < ROWS + 2; ++k) {
        int rr = r0 - 1 + k;
        rr = rr < 0 ? 0 : (rr > Ht - 1 ? Ht - 1 : rr);  // border rows zeroed below
        X[k] = *(const f4*)(x + (size_t)rr * Wd + c);
    }

    // ---- Halo: ONE masked load instruction covers both sides x all 18 rows.
    // lane k (k<18):  left halo f2 (cols cbase-2, cbase-1) of row r0-1+k
    // lane 32+k:      right halo f2 (cols cbase+256, +257) of row r0-1+k
    // Image-edge bands load nothing -> zeros (matches the zero-pad conv).
    f2 hl = {0.f, 0.f};
    {
        const int  hk   = lane & 31;
        const bool left = lane < 32;
        const bool valid = (hk < ROWS + 2) && (left ? (wc > 0) : (wc < 15));
        if (valid) {
            int rr = r0 - 1 + hk;
            rr = rr < 0 ? 0 : (rr > Ht - 1 ? Ht - 1 : rr);
            const int hc = left ? cbase - 2 : cbase + 256;
            hl = *(const f2*)(x + (size_t)rr * Wd + hc);
        }
    }
    // Per-lane halo t: lane (side*32 + o) holds the t-halo for output row r0+o.
    // shfl_down(1/2) stays within each side for all consumed lanes (o<=15 ->
    // source lanes <= 17 / 49).
    const float s1x = __shfl_down(hl.x, 1), s2x = __shfl_down(hl.x, 2);
    const float s1y = __shfl_down(hl.y, 1), s2y = __shfl_down(hl.y, 2);
    const float th1x = hl.x + 2.0f * s1x + s2x;   // t1 of halo col 0
    const float th1y = hl.y + 2.0f * s1y + s2y;   // t1 of halo col 1
    const float th2x = hl.x - s2x;                // t2 of halo col 0
    const float th2y = hl.y - s2y;                // t2 of halo col 1

    const float C1  = __uint_as_float(0x3CB851EDu);  // q > C1  <=> sqrt(q) > 0.15f
    const float C2B = __uint_as_float(0x3B23D709u);  // q > C2B <=> sqrt(q) >= 0.05f

    #pragma unroll
    for (int o = 0; o < ROWS; ++o) {
        const int r = r0 + o;
        f4 a = X[o], b = X[o + 1], cc = X[o + 2];

        // Vertical pass for own 4 cols: t1 = a+2b+c (gx), t2 = a-c (gy).
        float t1[4], t2[4];
        #pragma unroll
        for (int j = 0; j < 4; ++j) {
            t1[j] = a[j] + 2.0f * b[j] + cc[j];
            t2[j] = a[j] - cc[j];
        }

        // Halo broadcast: lane 0 wants left (lane o), lane 63 right (lane 32+o).
        const int hidx = (lane == 63) ? 32 + o : o;
        const float b1x = __shfl(th1x, hidx);
        const float b1y = __shfl(th1y, hidx);
        const float b2x = __shfl(th2x, hidx);
        const float b2y = __shfl(th2y, hidx);

        // Neighbor t via shuffle: left lane's cols 2,3 / right lane's cols 0,1.
        float l1a = __shfl_up(t1[2], 1),   l1b = __shfl_up(t1[3], 1);
        float l2a = __shfl_up(t2[2], 1),   l2b = __shfl_up(t2[3], 1);
        float r1a = __shfl_down(t1[0], 1), r1b = __shfl_down(t1[1], 1);
        float r2a = __shfl_down(t2[0], 1), r2b = __shfl_down(t2[1], 1);
        if (lane == 0)  { l1a = b1x; l1b = b1y; l2a = b2x; l2b = b2y; }
        if (lane == 63) { r1a = b1x; r1b = b1y; r2a = b2x; r2b = b2y; }

        // T index k = image col c + (k-2), k = 0..7.
        float T1[8] = {l1a, l1b, t1[0], t1[1], t1[2], t1[3], r1a, r1b};
        float T2[8] = {l2a, l2b, t2[0], t2[1], t2[2], t2[3], r2a, r2b};

        // Squared gradient magnitude q[i] at image col c + (i-1), i = 0..5.
        float q[6];
        #pragma unroll
        for (int i = 0; i < 6; ++i) {
            float gx = T1[i + 2] - T1[i];
            float gy = T2[i] + 2.0f * T2[i + 1] + T2[i + 2];
            q[i] = gx * gx + gy * gy;
        }

        // Hazard net: near-tie q pairs could flip >= after sqrt rounding.
        bool hazard = false;
        #pragma unroll
        for (int i = 0; i < 5; ++i) {
            int d = (int)(__float_as_uint(q[i + 1]) - __float_as_uint(q[i]));
            hazard |= ((unsigned)(d + 8) < 17u);
        }

        float acc[4];
        #pragma unroll
        for (int o2 = 0; o2 < 4; ++o2) {
            float qp = q[o2], qc = q[o2 + 1], qn = q[o2 + 2];
            bool keep = (qc >= qp) && (qc >= qn);
            acc[o2] = (keep && qc > C1) ? 255.0f : 0.0f;
            hazard |= (keep && qc > 0.0f && qc <= C2B);  // pass-through needs sqrt
        }

        if (__any(hazard)) {
            // Exact reference path (rare).
            float m[6];
            #pragma unroll
            for (int i = 0; i < 6; ++i) m[i] = sqrtf(q[i]);
            #pragma unroll
            for (int o2 = 0; o2 < 4; ++o2) {
                float mc = m[o2 + 1];
                bool keep = (mc >= m[o2]) && (mc >= m[o2 + 2]);
                float e = keep ? mc : 0.0f;
                acc[o2] = (e > 0.15f) ? 255.0f : ((e >= 0.05f) ? 0.0f : e);
            }
        }

        // Zero border shell, exactly as the reference.
        if (r == 0 || r == Ht - 1) {
            #pragma unroll
            for (int o2 = 0; o2 < 4; ++o2) acc[o2] = 0.0f;
        }
        if (wc == 0  && lane == 0)  acc[0] = 0.0f;
        if (wc == 15 && lane == 63) acc[3] = 0.0f;

        f4 v = {acc[0], acc[1], acc[2], acc[3]};
        __builtin_nontemporal_store(v, (f4*)(out + (size_t)r * Wd + c));
    }
}

extern "C" void kernel_launch(void* const* d_in, const int* in_sizes, int n_in,
                              void* d_out, int out_size, void* d_ws, size_t ws_size,
                              hipStream_t stream) {
    const float* x = (const float*)d_in[0];
    float* out = (float*)d_out;
    dim3 grid(16, Ht / (4 * ROWS));   // 16 col-bands x 64 blocks (4 waves x 16 rows)
    canny_kernel<<<grid, dim3(256), 0, stream>>>(x, out);
}